// Round 14
// baseline (104.313 us; speedup 1.0000x reference)
//
#include <hip/hip_runtime.h>
#include <stdint.h>

typedef short short8 __attribute__((ext_vector_type(8)));
typedef float f32x4 __attribute__((ext_vector_type(4)));

#define AS1 __attribute__((address_space(1)))
#define AS3 __attribute__((address_space(3)))

__device__ __forceinline__ void gl_lds16(const void* g, void* l) {
  __builtin_amdgcn_global_load_lds((const AS1 unsigned int*)g,
                                   (AS3 unsigned int*)l, 16, 0, 0);
}

__device__ __forceinline__ unsigned short f2bf(float f) {
  union { float f; unsigned int u; } v; v.f = f;
  return (unsigned short)((v.u + (((v.u >> 16) & 1u) + 0x7fffu)) >> 16);
}

// ---------------------------------------------------------------------------
// Pre-pass 1: x [16][256][64][64] fp32 NCHW -> x_t [16][64][64][256] bf16 NHWC
// ---------------------------------------------------------------------------
__global__ __launch_bounds__(256) void xpose_kernel(const float* __restrict__ x,
                                                    unsigned short* __restrict__ xt) {
  __shared__ float tile[64][68];
  const int bid = blockIdx.x;
  const int cchunk = bid & 3;
  const int y = (bid >> 2) & 63;
  const int b = bid >> 8;
  const int t = threadIdx.x;
  const int ci0 = cchunk * 64;

  const int cc = t >> 2;
  const int xo = (t & 3) * 16;
  const float* src = x + (((size_t)(b * 256 + ci0 + cc) * 64 + y) * 64 + xo);
  float4 v0 = ((const float4*)src)[0];
  float4 v1 = ((const float4*)src)[1];
  float4 v2 = ((const float4*)src)[2];
  float4 v3 = ((const float4*)src)[3];
  *(float4*)&tile[cc][xo + 0]  = v0;
  *(float4*)&tile[cc][xo + 4]  = v1;
  *(float4*)&tile[cc][xo + 8]  = v2;
  *(float4*)&tile[cc][xo + 12] = v3;
  __syncthreads();

  const int xpos = t >> 2;
  const int ccg = (t & 3) * 16;
  unsigned int pk[8];
#pragma unroll
  for (int e = 0; e < 8; ++e) {
    unsigned int lo = f2bf(tile[ccg + 2 * e][xpos]);
    unsigned int hi = f2bf(tile[ccg + 2 * e + 1][xpos]);
    pk[e] = lo | (hi << 16);
  }
  unsigned short* dst = xt + ((size_t)(b * 4096 + y * 64 + xpos) * 256 + ci0 + ccg);
  uint4 w0; w0.x = pk[0]; w0.y = pk[1]; w0.z = pk[2]; w0.w = pk[3];
  uint4 w1; w1.x = pk[4]; w1.y = pk[5]; w1.z = pk[6]; w1.w = pk[7];
  ((uint4*)dst)[0] = w0;
  ((uint4*)dst)[1] = w1;
}

// ---------------------------------------------------------------------------
// Pre-pass 2: w [256co][256ci][3][3] fp32 -> w_r [9 tap][256co][256ci] bf16
// ---------------------------------------------------------------------------
__global__ __launch_bounds__(256) void wpack_kernel(const float* __restrict__ w,
                                                    unsigned short* __restrict__ wrp) {
  const int idx = blockIdx.x * 256 + threadIdx.x;
  const int ci = idx & 255;
  const int co = (idx >> 8) & 255;
  const int p = idx >> 16;
  wrp[idx] = f2bf(w[(size_t)(co * 256 + ci) * 9 + p]);
}

// ---------------------------------------------------------------------------
// Main: R13's barrier-light pipeline + 2 blocks/CU (m114 cross-block filler).
// Tile 128co x 128px, 256 thr / 4 waves (2x2), wave 64x64, BK=64 dbuf 2x32KB.
// Per K-tile: p0 {read k1 frags | stage A+B(kt+1)} -> 16 MFMA k0;
//             p1 {8 MFMA k1} -> {vmcnt0;lgkm0;barrier; reload k0 from nbuf}
//                -> 8 MFMA k1 (covers the reload latency).
// The two co-resident blocks are in independent barrier domains -> one
// block's MFMA fills the other's drain bubble.
// ---------------------------------------------------------------------------
__global__ __launch_bounds__(256, 2) void conv_2blk(
    const unsigned short* __restrict__ xt,
    const unsigned short* __restrict__ wrp,
    const float* __restrict__ bias,
    float* __restrict__ out) {
  __shared__ unsigned short lds[2][16384];  // per buf: A [0,8192), B [8192,16384)

  const int tid = threadIdx.x;
  const int lane = tid & 63;
  const int wv = tid >> 6;      // 0..3
  const int wm = wv >> 1;       // co half of 128 (64)
  const int wn = wv & 1;        // px half of 128 (64)
  const int raw = blockIdx.x;   // 992 blocks
  const int wg = (raw & 7) * 124 + (raw >> 3);   // bijective XCD chunk swizzle
  const int cohalf = (wg >= 496) ? 1 : 0;
  const int pt = wg - cohalf * 496;              // 0..495
  const int b = pt / 31;
  const int oh0 = (pt - b * 31) * 2;             // 0..60
  const int co0 = cohalf * 128;

  // ---- staging statics: chunk = 32 rows x k64 = 4KB = 1 gl_lds16/thread ----
  const int crow = tid >> 3;            // 0..31
  const int cslot = tid & 7;            // 16B slot
  const int sw = cslot ^ (crow & 7);    // inverse-swizzled source slot
  const unsigned short* gA = wrp + (size_t)(co0 + crow) * 256 + sw * 8;
  const unsigned short* gB[4];
#pragma unroll
  for (int cb = 0; cb < 4; ++cb) {
    const int px = cb * 32 + crow;           // 0..127
    const int y = min(oh0 + (px >> 6), 61);  // y+kh <= 63
    const int xc = min(px & 63, 61);         // xc+kw <= 63
    gB[cb] = xt + ((size_t)(b * 64 + y) * 64 + xc) * 256 + sw * 8;
  }
  const unsigned dst_rc = crow * 64 + cslot * 8;  // + c*2048 elems

  // ---- fragment statics (0-conflict XOR swizzle, R7/R13-verified) ----
  const int l15 = lane & 15;
  int s8v[2];
  s8v[0] = (((lane >> 4)) ^ (lane & 7)) * 8;
  s8v[1] = (((lane >> 4) + 4) ^ (lane & 7)) * 8;
  int arow[4], brow[4];
#pragma unroll
  for (int m = 0; m < 4; ++m)
    arow[m] = (wm * 64 + m * 16 + l15) * 64;
#pragma unroll
  for (int n = 0; n < 4; ++n)
    brow[n] = 8192 + (wn * 64 + n * 16 + l15) * 64;

  auto stageA = [&](int kt2, unsigned short* bufp) {
    const int tap = kt2 >> 2, ci0 = (kt2 & 3) * 64;
    const unsigned short* g = gA + tap * 65536 + ci0;
#pragma unroll
    for (int c = 0; c < 4; ++c)
      gl_lds16(g + c * 8192, bufp + c * 2048 + dst_rc);   // +32 co rows per chunk
  };
  auto stageB = [&](int kt2, unsigned short* bufp) {
    const int tap = kt2 >> 2, ci0 = (kt2 & 3) * 64;
    const int kh = (tap * 11) >> 5, kw = tap - kh * 3;
    const int off = (kh * 64 + kw) * 256 + ci0;
#pragma unroll
    for (int cb = 0; cb < 4; ++cb)
      gl_lds16(gB[cb] + off, bufp + 8192 + cb * 2048 + dst_rc);
  };

  f32x4 acc[4][4] = {};
  unsigned short* buf0 = &lds[0][0];
  unsigned short* buf1 = &lds[1][0];

  // prologue: stage K-tile 0; drain; load k0 fragments
  stageA(0, buf0);
  stageB(0, buf0);
  asm volatile("s_waitcnt vmcnt(0)" ::: "memory");
  __builtin_amdgcn_s_barrier();

  short8 a_cur[4], b_cur[4], a_nxt[4], b_nxt[4];
#pragma unroll
  for (int q = 0; q < 4; ++q) a_cur[q] = *(const short8*)(buf0 + arow[q] + s8v[0]);
#pragma unroll
  for (int n = 0; n < 4; ++n) b_cur[n] = *(const short8*)(buf0 + brow[n] + s8v[0]);

  for (int kt = 0; kt < 36; ++kt) {
    const unsigned short* buf = (kt & 1) ? buf1 : buf0;
    unsigned short* nbuf = (kt & 1) ? buf0 : buf1;

    // ---- p0: issue k1 frags + stage A,B(kt+1); MFMA k0 (16) ----
#pragma unroll
    for (int q = 0; q < 4; ++q) a_nxt[q] = *(const short8*)(buf + arow[q] + s8v[1]);
#pragma unroll
    for (int n = 0; n < 4; ++n) b_nxt[n] = *(const short8*)(buf + brow[n] + s8v[1]);
    if (kt < 35) { stageA(kt + 1, nbuf); stageB(kt + 1, nbuf); }
    __builtin_amdgcn_sched_barrier(0);
    __builtin_amdgcn_s_setprio(1);
#pragma unroll
    for (int q = 0; q < 4; ++q)
#pragma unroll
      for (int n = 0; n < 4; ++n)
        acc[q][n] = __builtin_amdgcn_mfma_f32_16x16x32_bf16(a_cur[q], b_cur[n], acc[q][n], 0, 0, 0);
    __builtin_amdgcn_s_setprio(0);

    // ---- p1a: MFMA k1 n0-1 (8) ----
    __builtin_amdgcn_sched_barrier(0);
    __builtin_amdgcn_s_setprio(1);
#pragma unroll
    for (int q = 0; q < 4; ++q)
#pragma unroll
      for (int n = 0; n < 2; ++n)
        acc[q][n] = __builtin_amdgcn_mfma_f32_16x16x32_bf16(a_nxt[q], b_nxt[n], acc[q][n], 0, 0, 0);
    __builtin_amdgcn_s_setprio(0);

    // ---- K-tile boundary: drain + barrier; reload k0 from nbuf ----
    if (kt < 35) {
      asm volatile("s_waitcnt vmcnt(0)" ::: "memory");    // kt+1 stages landed
      asm volatile("s_waitcnt lgkmcnt(0)" ::: "memory");  // all my buf reads done
      __builtin_amdgcn_s_barrier();
#pragma unroll
      for (int q = 0; q < 4; ++q) a_cur[q] = *(const short8*)(nbuf + arow[q] + s8v[0]);
#pragma unroll
      for (int n = 0; n < 4; ++n) b_cur[n] = *(const short8*)(nbuf + brow[n] + s8v[0]);
    }

    // ---- p1b: MFMA k1 n2-3 (8) — covers the reload latency ----
    __builtin_amdgcn_sched_barrier(0);
    __builtin_amdgcn_s_setprio(1);
#pragma unroll
    for (int q = 0; q < 4; ++q)
#pragma unroll
      for (int n = 2; n < 4; ++n)
        acc[q][n] = __builtin_amdgcn_mfma_f32_16x16x32_bf16(a_nxt[q], b_nxt[n], acc[q][n], 0, 0, 0);
    __builtin_amdgcn_s_setprio(0);
  }

  // ---- epilogue: D col=lane&15 -> px, row=(lane>>4)*4+j -> co ----
  const int rb = (lane >> 4) * 4;
  const int colp = lane & 15;
#pragma unroll
  for (int m = 0; m < 4; ++m) {
    const int co = co0 + wm * 64 + m * 16 + rb;
    float bv[4];
#pragma unroll
    for (int j = 0; j < 4; ++j) bv[j] = bias[co + j];
#pragma unroll
    for (int n = 0; n < 4; ++n) {
      const int px = wn * 64 + n * 16 + colp;
      const int prow = px >> 6, ow = px & 63;
      const int oh = oh0 + prow;
      if (ow < 62) {
#pragma unroll
        for (int j = 0; j < 4; ++j)
          out[((size_t)(b * 256 + co + j) * 62 + oh) * 62 + ow] = acc[m][n][j] + bv[j];
      }
    }
  }
}

// ---------------------------------------------------------------------------
// Fallback: naive fp32 direct conv (used only if d_ws is too small)
// ---------------------------------------------------------------------------
__global__ __launch_bounds__(256) void conv_naive(const float* __restrict__ x,
                                                  const float* __restrict__ wgt,
                                                  const float* __restrict__ bias,
                                                  float* __restrict__ out) {
  const size_t idx = (size_t)blockIdx.x * 256 + threadIdx.x;
  if (idx >= (size_t)16 * 256 * 62 * 62) return;
  const int ow = (int)(idx % 62);
  size_t r = idx / 62;
  const int oh = (int)(r % 62); r /= 62;
  const int co = (int)(r % 256);
  const int b = (int)(r / 256);
  float s = bias[co];
  for (int ci = 0; ci < 256; ++ci) {
    const float* xp = x + ((size_t)(b * 256 + ci) * 64 + oh) * 64 + ow;
    const float* wp = wgt + (size_t)(co * 256 + ci) * 9;
#pragma unroll
    for (int kh = 0; kh < 3; ++kh)
#pragma unroll
      for (int kw = 0; kw < 3; ++kw)
        s += xp[kh * 64 + kw] * wp[kh * 3 + kw];
  }
  out[idx] = s;
}

extern "C" void kernel_launch(void* const* d_in, const int* in_sizes, int n_in,
                              void* d_out, int out_size, void* d_ws, size_t ws_size,
                              hipStream_t stream) {
  const float* x = (const float*)d_in[0];
  const float* wgt = (const float*)d_in[1];
  const float* bias = (const float*)d_in[2];
  float* out = (float*)d_out;

  const size_t xt_elems = (size_t)16 * 64 * 64 * 256;
  const size_t wr_elems = (size_t)9 * 256 * 256;
  const size_t need = (xt_elems + wr_elems) * sizeof(unsigned short);

  if (ws_size < need) {
    conv_naive<<<61504, 256, 0, stream>>>(x, wgt, bias, out);
    return;
  }

  unsigned short* xt = (unsigned short*)d_ws;
  unsigned short* wrp = xt + xt_elems;

  xpose_kernel<<<4096, 256, 0, stream>>>(x, xt);
  wpack_kernel<<<2304, 256, 0, stream>>>(wgt, wrp);
  conv_2blk<<<992, 256, 0, stream>>>(xt, wrp, bias, out);
}

// Round 15
// 93.721 us; speedup vs baseline: 1.1130x; 1.1130x over previous
//
#include <hip/hip_runtime.h>
#include <stdint.h>

typedef short short8 __attribute__((ext_vector_type(8)));
typedef float f32x4 __attribute__((ext_vector_type(4)));

#define AS1 __attribute__((address_space(1)))
#define AS3 __attribute__((address_space(3)))

__device__ __forceinline__ void gl_lds16(const void* g, void* l) {
  __builtin_amdgcn_global_load_lds((const AS1 unsigned int*)g,
                                   (AS3 unsigned int*)l, 16, 0, 0);
}

__device__ __forceinline__ unsigned short f2bf(float f) {
  union { float f; unsigned int u; } v; v.f = f;
  return (unsigned short)((v.u + (((v.u >> 16) & 1u) + 0x7fffu)) >> 16);
}

// ---------------------------------------------------------------------------
// Pre-pass 1: x [16][256][64][64] fp32 NCHW -> x_t [16][64][64][256] bf16 NHWC
// ---------------------------------------------------------------------------
__global__ __launch_bounds__(256) void xpose_kernel(const float* __restrict__ x,
                                                    unsigned short* __restrict__ xt) {
  __shared__ float tile[64][68];
  const int bid = blockIdx.x;
  const int cchunk = bid & 3;
  const int y = (bid >> 2) & 63;
  const int b = bid >> 8;
  const int t = threadIdx.x;
  const int ci0 = cchunk * 64;

  const int cc = t >> 2;
  const int xo = (t & 3) * 16;
  const float* src = x + (((size_t)(b * 256 + ci0 + cc) * 64 + y) * 64 + xo);
  float4 v0 = ((const float4*)src)[0];
  float4 v1 = ((const float4*)src)[1];
  float4 v2 = ((const float4*)src)[2];
  float4 v3 = ((const float4*)src)[3];
  *(float4*)&tile[cc][xo + 0]  = v0;
  *(float4*)&tile[cc][xo + 4]  = v1;
  *(float4*)&tile[cc][xo + 8]  = v2;
  *(float4*)&tile[cc][xo + 12] = v3;
  __syncthreads();

  const int xpos = t >> 2;
  const int ccg = (t & 3) * 16;
  unsigned int pk[8];
#pragma unroll
  for (int e = 0; e < 8; ++e) {
    unsigned int lo = f2bf(tile[ccg + 2 * e][xpos]);
    unsigned int hi = f2bf(tile[ccg + 2 * e + 1][xpos]);
    pk[e] = lo | (hi << 16);
  }
  unsigned short* dst = xt + ((size_t)(b * 4096 + y * 64 + xpos) * 256 + ci0 + ccg);
  uint4 w0; w0.x = pk[0]; w0.y = pk[1]; w0.z = pk[2]; w0.w = pk[3];
  uint4 w1; w1.x = pk[4]; w1.y = pk[5]; w1.z = pk[6]; w1.w = pk[7];
  ((uint4*)dst)[0] = w0;
  ((uint4*)dst)[1] = w1;
}

// ---------------------------------------------------------------------------
// Pre-pass 2: w [256co][256ci][3][3] fp32 -> w_r [9 tap][256co][256ci] bf16
// ---------------------------------------------------------------------------
__global__ __launch_bounds__(256) void wpack_kernel(const float* __restrict__ w,
                                                    unsigned short* __restrict__ wrp) {
  const int idx = blockIdx.x * 256 + threadIdx.x;
  const int ci = idx & 255;
  const int co = (idx >> 8) & 255;
  const int p = idx >> 16;
  wrp[idx] = f2bf(w[(size_t)(co * 256 + ci) * 9 + p]);
}

// ---------------------------------------------------------------------------
// Main: R13 pipeline + counted-everything 2-barrier K-tile.
//   p0: read A.k0.m4-7 | stage A,B(kt+1) (8 gl_lds, all early) | MFMA k0 m0-3
//   p1: read A.k1.m0-3 + B.k1            | MFMA k0 m4-7
//   p2: read A.k1.m4-7 | vmcnt(0) (2-phase slack) + barrier#1 | MFMA k1 m0-3
//   p3: preload kt+1 k0 frags from nbuf (globally valid after barrier#1)
//       | MFMA k1 m4-7 (16-MFMA cover) | lgkmcnt(8) counted + barrier#2
// No full lgkm drain; no end-of-tile VMEM drain. WAR: p0 stages write buffer
// (kt+1)&1 whose reads drained at kt-1's lgkmcnt(8); the 8 outstanding
// preload reads target buffer kt&1 (different) -> safe across barrier#2.
// ---------------------------------------------------------------------------
__global__ __launch_bounds__(512, 2) void conv_pipe2(
    const unsigned short* __restrict__ xt,
    const unsigned short* __restrict__ wrp,
    const float* __restrict__ bias,
    float* __restrict__ out) {
  __shared__ unsigned short lds[2][32768];  // per buf: A [0,16384), B [16384,32768)

  const int tid = threadIdx.x;
  const int lane = tid & 63;
  const int wv = tid >> 6;
  const int wm = wv >> 2;     // co half (128)
  const int wn = wv & 3;      // px quarter (64)
  const int bid = blockIdx.x;
  const int tile = (bid & 7) * 32 + (bid >> 3);  // bijective XCD swizzle (256%8==0)
  const int b = tile >> 4;
  const int oh0 = (tile & 15) * 4;

  // ---- staging statics (R13 verbatim) ----
  const int crow = tid >> 3;
  const int cslot = tid & 7;
  const int sw = cslot ^ (crow & 7);
  const unsigned short* gAbase = wrp + (size_t)crow * 256 + sw * 8;
  const unsigned short* gBbase[4];
#pragma unroll
  for (int cb = 0; cb < 4; ++cb) {
    const int y = min(oh0 + cb, 61);
    const int x = min(crow, 61);
    gBbase[cb] = xt + ((size_t)(b * 64 + y) * 64 + x) * 256 + sw * 8;
  }
  const unsigned dst_rc = crow * 64 + cslot * 8;

  // ---- fragment statics (R13 verbatim, measured 0-conflict) ----
  const int l15 = lane & 15;
  int s8v[2];
  s8v[0] = (((lane >> 4)) ^ (lane & 7)) * 8;
  s8v[1] = (((lane >> 4) + 4) ^ (lane & 7)) * 8;
  int arow[8], brow[4];
#pragma unroll
  for (int a = 0; a < 8; ++a)
    arow[a] = (wm * 128 + (a >> 2) * 64 + (a & 3) * 16 + l15) * 64;
#pragma unroll
  for (int n = 0; n < 4; ++n)
    brow[n] = 16384 + (wn * 64 + n * 16 + l15) * 64;

  auto stageA = [&](int kt2, unsigned short* bufp) {
    const int tap = kt2 >> 2, ci0 = (kt2 & 3) * 64;
    const unsigned short* g = gAbase + tap * 65536 + ci0;
#pragma unroll
    for (int c = 0; c < 4; ++c)
      gl_lds16(g + c * 16384, bufp + c * 4096 + dst_rc);
  };
  auto stageB = [&](int kt2, unsigned short* bufp) {
    const int tap = kt2 >> 2, ci0 = (kt2 & 3) * 64;
    const int kh = (tap * 11) >> 5, kw = tap - kh * 3;
    const int off = (kh * 64 + kw) * 256 + ci0;
#pragma unroll
    for (int cb = 0; cb < 4; ++cb)
      gl_lds16(gBbase[cb] + off, bufp + (4 + cb) * 4096 + dst_rc);
  };

  f32x4 acc[8][4] = {};
  unsigned short* buf0 = &lds[0][0];
  unsigned short* buf1 = &lds[1][0];

  // prologue: stage K-tile 0; drain; preload k0 fragments
  stageA(0, buf0);
  stageB(0, buf0);
  asm volatile("s_waitcnt vmcnt(0)" ::: "memory");
  __builtin_amdgcn_s_barrier();

  short8 a_cur[4], b_cur[4], a2[4], a3[4], b2[4], a4[4];
#pragma unroll
  for (int q = 0; q < 4; ++q) a_cur[q] = *(const short8*)(buf0 + arow[q] + s8v[0]);
#pragma unroll
  for (int n = 0; n < 4; ++n) b_cur[n] = *(const short8*)(buf0 + brow[n] + s8v[0]);

  for (int kt = 0; kt < 36; ++kt) {
    const unsigned short* buf = (kt & 1) ? buf1 : buf0;
    unsigned short* nbuf = (kt & 1) ? buf0 : buf1;

    // ---- p0: read A.k0.m4-7; stage kt+1 (all 8, max slack); MFMA k0 m0-3 ----
#pragma unroll
    for (int q = 0; q < 4; ++q) a2[q] = *(const short8*)(buf + arow[4 + q] + s8v[0]);
    if (kt < 35) { stageA(kt + 1, nbuf); stageB(kt + 1, nbuf); }
    __builtin_amdgcn_sched_barrier(0);
    __builtin_amdgcn_s_setprio(1);
#pragma unroll
    for (int q = 0; q < 4; ++q)
#pragma unroll
      for (int n = 0; n < 4; ++n)
        acc[q][n] = __builtin_amdgcn_mfma_f32_16x16x32_bf16(a_cur[q], b_cur[n], acc[q][n], 0, 0, 0);
    __builtin_amdgcn_s_setprio(0);

    // ---- p1: read A.k1.m0-3 + B.k1; MFMA k0 m4-7 ----
#pragma unroll
    for (int q = 0; q < 4; ++q) a3[q] = *(const short8*)(buf + arow[q] + s8v[1]);
#pragma unroll
    for (int n = 0; n < 4; ++n) b2[n] = *(const short8*)(buf + brow[n] + s8v[1]);
    __builtin_amdgcn_sched_barrier(0);
    __builtin_amdgcn_s_setprio(1);
#pragma unroll
    for (int q = 0; q < 4; ++q)
#pragma unroll
      for (int n = 0; n < 4; ++n)
        acc[4 + q][n] = __builtin_amdgcn_mfma_f32_16x16x32_bf16(a2[q], b_cur[n], acc[4 + q][n], 0, 0, 0);
    __builtin_amdgcn_s_setprio(0);

    // ---- p2: read A.k1.m4-7; vmcnt(0)+barrier#1 (stages globally landed); MFMA k1 m0-3 ----
#pragma unroll
    for (int q = 0; q < 4; ++q) a4[q] = *(const short8*)(buf + arow[4 + q] + s8v[1]);
    asm volatile("s_waitcnt vmcnt(0)" ::: "memory");   // ~2 phases of slack
    __builtin_amdgcn_s_barrier();                      // barrier#1: nbuf valid for all
    __builtin_amdgcn_sched_barrier(0);
    __builtin_amdgcn_s_setprio(1);
#pragma unroll
    for (int q = 0; q < 4; ++q)
#pragma unroll
      for (int n = 0; n < 4; ++n)
        acc[q][n] = __builtin_amdgcn_mfma_f32_16x16x32_bf16(a3[q], b2[n], acc[q][n], 0, 0, 0);
    __builtin_amdgcn_s_setprio(0);

    // ---- p3: preload kt+1 k0 frags from nbuf; MFMA k1 m4-7 (covers preload);
    //      counted lgkmcnt(8) + barrier#2 ----
    if (kt < 35) {
#pragma unroll
      for (int q = 0; q < 4; ++q) a_cur[q] = *(const short8*)(nbuf + arow[q] + s8v[0]);
#pragma unroll
      for (int n = 0; n < 4; ++n) b_cur[n] = *(const short8*)(nbuf + brow[n] + s8v[0]);
    }
    __builtin_amdgcn_sched_barrier(0);
    __builtin_amdgcn_s_setprio(1);
#pragma unroll
    for (int q = 0; q < 4; ++q)
#pragma unroll
      for (int n = 0; n < 4; ++n)
        acc[4 + q][n] = __builtin_amdgcn_mfma_f32_16x16x32_bf16(a4[q], b2[n], acc[4 + q][n], 0, 0, 0);
    __builtin_amdgcn_s_setprio(0);
    if (kt < 35) {
      // drain this buf's reads (older, in-order DS); the 8 nbuf preload reads
      // legally remain outstanding across the barrier (they target buffer kt&1^1,
      // while next p0's stages write buffer kt&1 -> no WAR).
      asm volatile("s_waitcnt lgkmcnt(8)" ::: "memory");
      __builtin_amdgcn_s_barrier();                    // barrier#2
    }
  }

  // ---- epilogue (R13 verbatim): D col=lane&15 -> px, row=(lane>>4)*4+j -> co ----
  const int rb = (lane >> 4) * 4;
  const int colp = lane & 15;
#pragma unroll
  for (int a = 0; a < 8; ++a) {
    const int co = wm * 128 + (a >> 2) * 64 + (a & 3) * 16 + rb;
    float bv[4];
#pragma unroll
    for (int j = 0; j < 4; ++j) bv[j] = bias[co + j];
#pragma unroll
    for (int n = 0; n < 4; ++n) {
      const int px = wn * 64 + n * 16 + colp;
      const int prow = px >> 6, ow = px & 63;
      const int oh = oh0 + prow;
      if (ow < 62 && oh < 62) {
#pragma unroll
        for (int j = 0; j < 4; ++j)
          out[((size_t)(b * 256 + co + j) * 62 + oh) * 62 + ow] = acc[a][n][j] + bv[j];
      }
    }
  }
}

// ---------------------------------------------------------------------------
// Fallback: naive fp32 direct conv (used only if d_ws is too small)
// ---------------------------------------------------------------------------
__global__ __launch_bounds__(256) void conv_naive(const float* __restrict__ x,
                                                  const float* __restrict__ wgt,
                                                  const float* __restrict__ bias,
                                                  float* __restrict__ out) {
  const size_t idx = (size_t)blockIdx.x * 256 + threadIdx.x;
  if (idx >= (size_t)16 * 256 * 62 * 62) return;
  const int ow = (int)(idx % 62);
  size_t r = idx / 62;
  const int oh = (int)(r % 62); r /= 62;
  const int co = (int)(r % 256);
  const int b = (int)(r / 256);
  float s = bias[co];
  for (int ci = 0; ci < 256; ++ci) {
    const float* xp = x + ((size_t)(b * 256 + ci) * 64 + oh) * 64 + ow;
    const float* wp = wgt + (size_t)(co * 256 + ci) * 9;
#pragma unroll
    for (int kh = 0; kh < 3; ++kh)
#pragma unroll
      for (int kw = 0; kw < 3; ++kw)
        s += xp[kh * 64 + kw] * wp[kh * 3 + kw];
  }
  out[idx] = s;
}

extern "C" void kernel_launch(void* const* d_in, const int* in_sizes, int n_in,
                              void* d_out, int out_size, void* d_ws, size_t ws_size,
                              hipStream_t stream) {
  const float* x = (const float*)d_in[0];
  const float* wgt = (const float*)d_in[1];
  const float* bias = (const float*)d_in[2];
  float* out = (float*)d_out;

  const size_t xt_elems = (size_t)16 * 64 * 64 * 256;
  const size_t wr_elems = (size_t)9 * 256 * 256;
  const size_t need = (xt_elems + wr_elems) * sizeof(unsigned short);

  if (ws_size < need) {
    conv_naive<<<61504, 256, 0, stream>>>(x, wgt, bias, out);
    return;
  }

  unsigned short* xt = (unsigned short*)d_ws;
  unsigned short* wrp = xt + xt_elems;

  xpose_kernel<<<4096, 256, 0, stream>>>(x, xt);
  wpack_kernel<<<2304, 256, 0, stream>>>(wgt, wrp);
  conv_pipe2<<<256, 512, 0, stream>>>(xt, wrp, bias, out);
}